// Round 4
// baseline (82575.568 us; speedup 1.0000x reference)
//
#include <hip/hip_runtime.h>

// Problem constants
#define Tt    1024
#define INF   256
#define Hh    768
#define OUTF  128

#define NWG_L0  96
#define NWG_L1  96
#define NWG_LIN 4
#define NWG     196
#define NTHR    1024

typedef unsigned int       u32;
typedef unsigned long long u64;
typedef unsigned short     u16;
typedef __attribute__((ext_vector_type(8))) short bf16x8;   // 8 bf16 = 4 VGPRs
typedef __attribute__((ext_vector_type(4))) float f32x4;    // MFMA C/D

// ws layout (bytes): [0,1024) slots[256]; [1024] go; [2048) hA ring 2x48KB; then hB ring.
#define HPS 24576   // ring parity stride in u16 (32*768)

// LDS: one 49,664 B union.
//  Phase A (stage+mfma): act[32 rows][776 bf16]  (stride 1552 B; 388 dw = 4 mod 32 -> uniform banks)
//  Phase B (reduce):     red[32 slabs][16 n][16 m] f32 = 32 KB ; part[32][33] f32 @33024 ; hpack @37376
#define ASTR_B 1552

__device__ __forceinline__ float sigf(float v){ return 1.0f/(1.0f+__expf(-v)); }
__device__ __forceinline__ u16 f2bf(float f){           // round-nearest-even
    u32 u = __float_as_uint(f);
    return (u16)((u + 0x7fffu + ((u>>16)&1u)) >> 16);
}
// LLC-coherent (L2-bypassing) accesses for cross-WG data (R3-proven).
__device__ __forceinline__ u64 ld64ws(const u16* p){
    return __hip_atomic_load((const u64*)p, __ATOMIC_RELAXED, __HIP_MEMORY_SCOPE_AGENT);
}
__device__ __forceinline__ void st32ws(u16* p, u32 v){
    __hip_atomic_store((u32*)p, v, __ATOMIC_RELAXED, __HIP_MEMORY_SCOPE_AGENT);
}
__device__ __forceinline__ u32 ldu32(const u32* p){
    return __hip_atomic_load(p, __ATOMIC_RELAXED, __HIP_MEMORY_SCOPE_AGENT);
}
__device__ __forceinline__ void stu32(u32* p, u32 v){
    __hip_atomic_store(p, v, __ATOMIC_RELAXED, __HIP_MEMORY_SCOPE_AGENT);
}

__global__ void prologue(char* ws){
    int i = blockIdx.x * 256 + threadIdx.x;
    if (i < 49664) ((u32*)ws)[i] = 0u;   // slots+go+hA+hB
}

__device__ __forceinline__ bf16x8 load8w(const float* p){
    float4 v0 = *(const float4*)(p);
    float4 v1 = *(const float4*)(p + 4);
    bf16x8 r;
    r[0]=(short)f2bf(v0.x); r[1]=(short)f2bf(v0.y); r[2]=(short)f2bf(v0.z); r[3]=(short)f2bf(v0.w);
    r[4]=(short)f2bf(v1.x); r[5]=(short)f2bf(v1.y); r[6]=(short)f2bf(v1.z); r[7]=(short)f2bf(v1.w);
    return r;
}

__global__ __launch_bounds__(NTHR) void lstm_persist(
    const float* __restrict__ x,
    const float* __restrict__ Wih0, const float* __restrict__ Whh0,
    const float* __restrict__ bih0, const float* __restrict__ bhh0,
    const float* __restrict__ Wih1, const float* __restrict__ Whh1,
    const float* __restrict__ bih1, const float* __restrict__ bhh1,
    const float* __restrict__ Wlin, const float* __restrict__ blin,
    float* __restrict__ out, char* ws)
{
    __shared__ __align__(16) char smem[49664];
    char*  actb  = smem;
    float* red   = (float*)smem;
    float* part  = (float*)(smem + 33024);
    u16*   hpack = (u16*)(smem + 37376);

    const int wg  = blockIdx.x;
    const int tid = threadIdx.x;
    const int lane = tid & 63, w = tid >> 6;
    const int quad = lane >> 4, nl = lane & 15;
    const int nt = w >> 3, ks = w & 7;
    const int b3 = tid >> 5, q = tid & 31;     // staging map: row b3, col-block q

    u32* slots = (u32*)ws;
    u32* go    = (u32*)(ws + 1024);
    u16* hA    = (u16*)(ws + 2048);
    u16* hB    = (u16*)(ws + 2048 + 98304);

    const int role  = (wg < NWG_L0) ? 0 : ((wg < NWG_L0 + NWG_L1) ? 1 : 2);
    const int jbase = (role == 0) ? wg * 8 : ((role == 1) ? (wg - NWG_L0) * 8 : 0);
    const int obase = (role == 2) ? (wg - NWG_L0 - NWG_L1) * 32 : 0;

    // ---- register-resident weights: B-frags, loaded ONCE ----
    // wave (nt,ks): rows r_wg = nt*16 + (lane&15); K-slice ks of 8.
    // B-frag layout: n = lane&15, k = quad*8 + j  (j = frag elem 0..7)
    const int r_wg = nt * 16 + nl;
    bf16x8 bfr[6];
    int nchunk, nfc, SL;   // chunks per step, frags per chunk, K-slice per wave per chunk
    if (role == 0) {
        nchunk = 2; nfc = 2; SL = 64;
        const int gate = r_wg >> 3, jl = r_wg & 7;
        const int grow = gate * 768 + jbase + jl;
        #pragma unroll
        for (int fi = 0; fi < 4; ++fi) {
            const int c = fi >> 1, fc = fi & 1;
            const int ka = c * 512 + ks * 64 + fc * 32 + quad * 8;   // abs K: [x(256); hA(768)]
            const float* p = (ka < 256) ? (Wih0 + (size_t)grow * 256 + ka)
                                        : (Whh0 + (size_t)grow * 768 + (ka - 256));
            bfr[fi] = load8w(p);
        }
    } else if (role == 1) {
        nchunk = 2; nfc = 3; SL = 96;
        const int gate = r_wg >> 3, jl = r_wg & 7;
        const int grow = gate * 768 + jbase + jl;
        #pragma unroll
        for (int fi = 0; fi < 6; ++fi) {
            const int c = fi / 3, fc = fi % 3;
            const int ka = c * 768 + ks * 96 + fc * 32 + quad * 8;   // abs K: [hA; hB]
            const float* p = (ka < 768) ? (Wih1 + (size_t)grow * 768 + ka)
                                        : (Whh1 + (size_t)grow * 768 + (ka - 768));
            bfr[fi] = load8w(p);
        }
    } else {
        nchunk = 1; nfc = 3; SL = 96;
        #pragma unroll
        for (int fi = 0; fi < 3; ++fi) {
            const int ka = ks * 96 + fi * 32 + quad * 8;
            bfr[fi] = load8w(Wlin + (size_t)(obase + r_wg) * 768 + ka);
        }
    }

    // gate-thread constants + c-state in registers
    float bs0 = 0.f, bs1 = 0.f, bs2 = 0.f, bs3 = 0.f, creg = 0.f, blin_r = 0.f;
    if (role < 2 && tid < 256) {
        const int jg = jbase + (tid >> 5);
        const float* bi = (role == 0) ? bih0 : bih1;
        const float* bh = (role == 0) ? bhh0 : bhh1;
        bs0 = bi[jg]        + bh[jg];
        bs1 = bi[768 + jg]  + bh[768 + jg];
        bs2 = bi[1536 + jg] + bh[1536 + jg];
        bs3 = bi[2304 + jg] + bh[2304 + jg];
    }
    if (role == 2) blin_r = blin[obase + (tid >> 5)];

    for (int s = 0; s < Tt + 2; ++s) {
        bool active;
        if      (role == 0) active = (s < Tt);
        else if (role == 1) active = (s >= 1 && s <= Tt);
        else                active = (s >= 2);

        if (active) {
            f32x4 acc0 = {0.f,0.f,0.f,0.f}, acc1 = {0.f,0.f,0.f,0.f};

            for (int c = 0; c < nchunk; ++c) {
                // ---------- stage chunk c into act LDS (rows=b, bf16, stride 1552 B) ----------
                if (role == 0) {
                    if (c == 0) {
                        // k_c [0,256) = x[:,s,:] fp32->bf16 ; k_c [256,512) = hA(prev)[0..256)
                        const float* xs = x + ((size_t)b3 * Tt + s) * INF + q * 8;
                        float4 v0 = *(const float4*)xs, v1 = *(const float4*)(xs + 4);
                        u64 lo = (u64)f2bf(v0.x) | ((u64)f2bf(v0.y)<<16) | ((u64)f2bf(v0.z)<<32) | ((u64)f2bf(v0.w)<<48);
                        u64 hi = (u64)f2bf(v1.x) | ((u64)f2bf(v1.y)<<16) | ((u64)f2bf(v1.z)<<32) | ((u64)f2bf(v1.w)<<48);
                        u64* dx = (u64*)(actb + b3 * ASTR_B + q * 16);
                        dx[0] = lo; dx[1] = hi;
                        const u16* src = hA + (size_t)((s + 1) & 1) * HPS + b3 * 768 + q * 8;
                        u64 h0 = ld64ws(src), h1 = ld64ws(src + 4);
                        u64* dh = (u64*)(actb + b3 * ASTR_B + (256 + q * 8) * 2);
                        dh[0] = h0; dh[1] = h1;
                    } else {
                        // k_c [0,512) = hA(prev)[256..768)
                        const u16* base = hA + (size_t)((s + 1) & 1) * HPS + b3 * 768 + 256;
                        #pragma unroll
                        for (int p = 0; p < 2; ++p) {
                            const int k = q * 8 + 256 * p;
                            u64 h0 = ld64ws(base + k), h1 = ld64ws(base + k + 4);
                            u64* d = (u64*)(actb + b3 * ASTR_B + k * 2);
                            d[0] = h0; d[1] = h1;
                        }
                    }
                } else {
                    const u16* ringp;
                    if (role == 1) {
                        const int u = s - 1;
                        ringp = (c == 0) ? (hA + (size_t)(u & 1) * HPS)
                                         : (hB + (size_t)((u + 1) & 1) * HPS);
                    } else {
                        ringp = hB + (size_t)((s - 2) & 1) * HPS;
                    }
                    const u16* base = ringp + b3 * 768;
                    #pragma unroll
                    for (int p = 0; p < 3; ++p) {
                        const int k = q * 8 + 256 * p;
                        u64 h0 = ld64ws(base + k), h1 = ld64ws(base + k + 4);
                        u64* d = (u64*)(actb + b3 * ASTR_B + k * 2);
                        d[0] = h0; d[1] = h1;
                    }
                }
                __syncthreads();

                // ---------- MFMA over this chunk ----------
                #pragma unroll
                for (int fc = 0; fc < 3; ++fc) {
                    if (fc >= nfc) break;
                    const int koff = ks * SL + fc * 32 + quad * 8;   // A: m=lane&15, k=quad*8+j
                    bf16x8 a0 = *(const bf16x8*)(actb + nl * ASTR_B + koff * 2);
                    bf16x8 a1 = *(const bf16x8*)(actb + (16 + nl) * ASTR_B + koff * 2);
                    const int fi = c * nfc + fc;
                    acc0 = __builtin_amdgcn_mfma_f32_16x16x32_bf16(a0, bfr[fi], acc0, 0, 0, 0);
                    acc1 = __builtin_amdgcn_mfma_f32_16x16x32_bf16(a1, bfr[fi], acc1, 0, 0, 0);
                }
                __syncthreads();
            }

            // ---------- C-tiles -> red LDS (aliases act; all mfma A-reads done) ----------
            // D: row(m=batch)=quad*4+reg, col(n=gate-row)=lane&15. red[slab][n][m], slab=ks*4+nt*2+mt.
            *(f32x4*)(red + (size_t)(ks * 4 + nt * 2 + 0) * 256 + nl * 16 + quad * 4) = acc0;
            *(f32x4*)(red + (size_t)(ks * 4 + nt * 2 + 1) * 256 + nl * 16 + quad * 4) = acc1;
            __syncthreads();

            // ---------- K-reduction: thread (r,b) sums 8 slabs ----------
            const int r = tid >> 5, bb = tid & 31;
            const int ntr = r >> 4, nr = r & 15, mtr = bb >> 4, mr = bb & 15;
            float p = 0.f;
            #pragma unroll
            for (int k2 = 0; k2 < 8; ++k2)
                p += red[(size_t)(k2 * 4 + ntr * 2 + mtr) * 256 + nr * 16 + mr];

            if (role == 2) {
                out[((size_t)bb * Tt + (s - 2)) * OUTF + obase + r] = p + blin_r;
                __syncthreads();  // keep sync count uniform with role<2 path? (no: role is WG-uniform)
            } else {
                part[r * 33 + bb] = p;
                __syncthreads();
                // ---------- gates ----------
                if (tid < 256) {
                    const int jl = tid >> 5, b2 = tid & 31;
                    const float pi = bs0 + part[(0 * 8 + jl) * 33 + b2];
                    const float pf = bs1 + part[(1 * 8 + jl) * 33 + b2];
                    const float pg = bs2 + part[(2 * 8 + jl) * 33 + b2];
                    const float po = bs3 + part[(3 * 8 + jl) * 33 + b2];
                    const float ig = sigf(pi), fg = sigf(pf);
                    const float gv = tanhf(pg), og = sigf(po);
                    creg = fg * creg + ig * gv;
                    hpack[jl * 32 + b2] = f2bf(og * tanhf(creg));
                }
                __syncthreads();
                if (tid < 128) {   // pack j-pairs -> u32 LLC store into ring
                    const int pp = tid >> 5, b2 = tid & 31;
                    const u32 val = (u32)hpack[(2 * pp) * 32 + b2] | ((u32)hpack[(2 * pp + 1) * 32 + b2] << 16);
                    u16* dst = (role == 0) ? (hA + (size_t)(s & 1) * HPS)
                                           : (hB + (size_t)((s - 1) & 1) * HPS);
                    st32ws(dst + b2 * 768 + jbase + 2 * pp, val);
                }
            }
        }

        // ---------- grid barrier (mailbox, no cache maintenance) ----------
        __syncthreads();
        const u32 tgt = (u32)(s + 1);
        if (wg == 0) {
            if (tid < NWG) {
                if (tid == 0) stu32(slots, tgt);
                int guard = 0;
                while (ldu32(slots + tid) < tgt && guard < (1 << 28)) {
                    __builtin_amdgcn_s_sleep(2); ++guard;
                }
            }
            __syncthreads();
            if (tid == 0) stu32(go, tgt);
        } else {
            if (tid == 0) {
                stu32(slots + wg, tgt);
                int guard = 0;
                while (ldu32(go) < tgt && guard < (1 << 28)) {
                    __builtin_amdgcn_s_sleep(2); ++guard;
                }
            }
            __syncthreads();
        }
    }
}

extern "C" void kernel_launch(void* const* d_in, const int* in_sizes, int n_in,
                              void* d_out, int out_size, void* d_ws, size_t ws_size,
                              hipStream_t stream)
{
    const float* x    = (const float*)d_in[0];
    const float* Wih0 = (const float*)d_in[1];
    const float* Whh0 = (const float*)d_in[2];
    const float* bih0 = (const float*)d_in[3];
    const float* bhh0 = (const float*)d_in[4];
    const float* Wih1 = (const float*)d_in[5];
    const float* Whh1 = (const float*)d_in[6];
    const float* bih1 = (const float*)d_in[7];
    const float* bhh1 = (const float*)d_in[8];
    const float* Wlin = (const float*)d_in[9];
    const float* blin = (const float*)d_in[10];
    float* out = (float*)d_out;
    char*  ws  = (char*)d_ws;   // uses ~200 KB

    hipLaunchKernelGGL(prologue, dim3(194), dim3(256), 0, stream, ws);
    hipLaunchKernelGGL(lstm_persist, dim3(NWG), dim3(NTHR), 0, stream,
                       x, Wih0, Whh0, bih0, bhh0,
                       Wih1, Whh1, bih1, bhh1,
                       Wlin, blin, out, ws);
}

// Round 5
// 6882.201 us; speedup vs baseline: 11.9984x; 11.9984x over previous
//
#include <hip/hip_runtime.h>

// Problem constants
#define Tt    1024
#define INF   256
#define Hh    768
#define OUTF  128

// Grid: 48 L0 + 48 L1 + 2 LIN compute WGs + 1 coordinator WG. 1024 thr each.
#define NWG_L0  48
#define NWG_L1  48
#define NWG_LIN 2
#define NWGC    (NWG_L0 + NWG_L1 + NWG_LIN)   // 98 compute WGs
#define NWG     (NWGC + 1)                     // +1 coordinator
#define NTHR    1024

typedef unsigned int       u32;
typedef unsigned long long u64;
typedef unsigned short     u16;
typedef __attribute__((ext_vector_type(8))) short bf16x8;   // 8 bf16 = 4 VGPRs
typedef __attribute__((ext_vector_type(4))) float f32x4;    // MFMA C/D

// ws layout (bytes). Every flag on a PRIVATE 128-B line (1 writer, 1 reader).
#define PROG_OFF 0         // prog[wg] at ws + wg*128        (writer: WG wg leader; reader: coordinator thread wg)
#define GO_OFF   16384     // go[wg]   at ws + GO_OFF+wg*128 (writer: coordinator thread wg; reader: WG wg leader)
#define HA_OFF   32768     // hA ring: [2 parity][32 b][768 j] bf16 (2*48 KB)
#define HB_OFF   131072    // hB ring: same
#define WS_BYTES 229376
#define HPS 24576          // ring parity stride in u16 (32*768)

#define ASTR_B 1552        // act LDS row stride in bytes (776 bf16)

__device__ __forceinline__ float sigf(float v){ return 1.0f/(1.0f+__expf(-v)); }
__device__ __forceinline__ u16 f2bf(float f){           // round-nearest-even
    u32 u = __float_as_uint(f);
    return (u16)((u + 0x7fffu + ((u>>16)&1u)) >> 16);
}
// LLC-coherent (cache-bypassing) accesses for cross-WG data.
__device__ __forceinline__ u64 ld64ws(const u16* p){
    return __hip_atomic_load((const u64*)p, __ATOMIC_RELAXED, __HIP_MEMORY_SCOPE_AGENT);
}
__device__ __forceinline__ void st32ws(u16* p, u32 v){
    __hip_atomic_store((u32*)p, v, __ATOMIC_RELAXED, __HIP_MEMORY_SCOPE_AGENT);
}
__device__ __forceinline__ u32 ldu32(const u32* p){
    return __hip_atomic_load(p, __ATOMIC_RELAXED, __HIP_MEMORY_SCOPE_AGENT);
}
__device__ __forceinline__ void stu32(u32* p, u32 v){
    __hip_atomic_store(p, v, __ATOMIC_RELAXED, __HIP_MEMORY_SCOPE_AGENT);
}

__global__ void prologue(char* ws){
    int i = blockIdx.x * 256 + threadIdx.x;
    if (i < WS_BYTES / 4) ((u32*)ws)[i] = 0u;   // flags + rings
}

__device__ __forceinline__ bf16x8 load8w(const float* p){
    float4 v0 = *(const float4*)(p);
    float4 v1 = *(const float4*)(p + 4);
    bf16x8 r;
    r[0]=(short)f2bf(v0.x); r[1]=(short)f2bf(v0.y); r[2]=(short)f2bf(v0.z); r[3]=(short)f2bf(v0.w);
    r[4]=(short)f2bf(v1.x); r[5]=(short)f2bf(v1.y); r[6]=(short)f2bf(v1.z); r[7]=(short)f2bf(v1.w);
    return r;
}

__global__ __launch_bounds__(NTHR) void lstm_persist(
    const float* __restrict__ x,
    const float* __restrict__ Wih0, const float* __restrict__ Whh0,
    const float* __restrict__ bih0, const float* __restrict__ bhh0,
    const float* __restrict__ Wih1, const float* __restrict__ Whh1,
    const float* __restrict__ bih1, const float* __restrict__ bhh1,
    const float* __restrict__ Wlin, const float* __restrict__ blin,
    float* __restrict__ out, char* ws)
{
    u32* prog = (u32*)(ws + PROG_OFF);
    u32* gol  = (u32*)(ws + GO_OFF);
    u16* hA   = (u16*)(ws + HA_OFF);
    u16* hB   = (u16*)(ws + HB_OFF);

    const int wg  = blockIdx.x;
    const int tid = threadIdx.x;

    // ================= coordinator WG: gather 98 private lines, fan out 98 =================
    if (wg == NWGC) {
        for (int s = 0; s < Tt + 2; ++s) {
            if (tid < NWGC) {
                const u32 tg = (u32)(s + 1);
                while (ldu32(prog + tid * 32) < tg) __builtin_amdgcn_s_sleep(1);
            }
            __syncthreads();
            if (tid < NWGC) stu32(gol + tid * 32, (u32)(s + 1));
        }
        return;
    }

    // ================= compute WGs =================
    __shared__ __align__(16) char smem[49664];
    char*  actb  = smem;                       // [32 b][776 bf16] staging (per chunk)
    float* red   = (float*)smem;               // 32 KB: [(nt*2+mt)*4+ks][16 n][16 m] f32 (act dead by then)
    float* part  = (float*)(smem + 33024);     // [64 rows][33] f32 (no overlap with red)
    u16*   hpack = (u16*)(smem + 41472);       // [16 j][32 b] bf16

    const int lane = tid & 63, w = tid >> 6;
    const int quad = lane >> 4, nl = lane & 15;
    const int nt = w >> 2, ks = w & 3;         // n-tile 0..3 (== gate for L0/L1), K-slice 0..3
    const int b3 = tid >> 5, q = tid & 31;     // staging map: batch row, col-block

    const int role  = (wg < NWG_L0) ? 0 : ((wg < NWG_L0 + NWG_L1) ? 1 : 2);
    const int jbase = (role == 0) ? wg * 16 : ((role == 1) ? (wg - NWG_L0) * 16 : 0);
    const int obase = (role == 2) ? (wg - NWG_L0 - NWG_L1) * 64 : 0;

    // ---- register-resident bf16 weights (B-frags), loaded ONCE ----
    // B-frag layout (R4-verified): n = lane&15, k = quad*8 + j.
    // Wave (nt,ks) owns weight rows r = nt*16 + nl, K-slice ks.
    bf16x8 bfr[12];
    if (role == 0) {
        const int grow = nt * Hh + jbase + nl;          // gate=nt, j=jbase+nl
        #pragma unroll
        for (int fi = 0; fi < 8; ++fi) {
            const int c = fi >> 2, fc = fi & 3;
            const int ka = c * 512 + ks * 128 + fc * 32 + quad * 8;   // K: [x(256); hA(768)]
            const float* p = (ka < 256) ? (Wih0 + (size_t)grow * 256 + ka)
                                        : (Whh0 + (size_t)grow * 768 + (ka - 256));
            bfr[fi] = load8w(p);
        }
    } else if (role == 1) {
        const int grow = nt * Hh + jbase + nl;
        #pragma unroll
        for (int fi = 0; fi < 12; ++fi) {
            const int c = fi / 6, fc = fi % 6;
            const int ka = c * 768 + ks * 192 + fc * 32 + quad * 8;   // K: [hA; hB]
            const float* p = (ka < 768) ? (Wih1 + (size_t)grow * 768 + ka)
                                        : (Whh1 + (size_t)grow * 768 + (ka - 768));
            bfr[fi] = load8w(p);
        }
    } else {
        const int row = obase + nt * 16 + nl;
        #pragma unroll
        for (int fi = 0; fi < 6; ++fi) {
            const int ka = ks * 192 + fi * 32 + quad * 8;
            bfr[fi] = load8w(Wlin + (size_t)row * 768 + ka);
        }
    }

    // gate-thread constants + c-state in registers (thread owns (jl,b) forever)
    float bs0 = 0.f, bs1 = 0.f, bs2 = 0.f, bs3 = 0.f, creg = 0.f, bl0 = 0.f, bl1 = 0.f;
    if (role < 2 && tid < 512) {
        const int jg = jbase + (tid >> 5);
        const float* bi = (role == 0) ? bih0 : bih1;
        const float* bh = (role == 0) ? bhh0 : bhh1;
        bs0 = bi[jg]        + bh[jg];
        bs1 = bi[768 + jg]  + bh[768 + jg];
        bs2 = bi[1536 + jg] + bh[1536 + jg];
        bs3 = bi[2304 + jg] + bh[2304 + jg];
    }
    if (role == 2) {
        bl0 = blin[obase + (tid >> 5)];
        bl1 = blin[obase + 32 + (tid >> 5)];
    }

    for (int s = 0; s < Tt + 2; ++s) {
        // ---- wait for release of step s (go[wg] is a private line) ----
        if (s > 0) {
            if (tid == 0) {
                while (ldu32(gol + wg * 32) < (u32)s) __builtin_amdgcn_s_sleep(1);
            }
            __syncthreads();
        }

        const bool active = (role == 0) ? (s < Tt)
                          : (role == 1) ? (s >= 1 && s <= Tt)
                          :               (s >= 2);

        if (active) {
            f32x4 acc0 = {0.f,0.f,0.f,0.f}, acc1 = {0.f,0.f,0.f,0.f};

            if (role == 0) {
                // ---- chunk 0: K[0,512) = x(t) ++ hA(t-1)[0,256) ----
                {
                    const float* xs = x + ((size_t)b3 * Tt + s) * INF + q * 8;
                    float4 v0 = *(const float4*)xs, v1 = *(const float4*)(xs + 4);
                    u64 lo = (u64)f2bf(v0.x) | ((u64)f2bf(v0.y)<<16) | ((u64)f2bf(v0.z)<<32) | ((u64)f2bf(v0.w)<<48);
                    u64 hi = (u64)f2bf(v1.x) | ((u64)f2bf(v1.y)<<16) | ((u64)f2bf(v1.z)<<32) | ((u64)f2bf(v1.w)<<48);
                    u64* dx = (u64*)(actb + b3 * ASTR_B + q * 16);
                    dx[0] = lo; dx[1] = hi;
                    const u16* src = hA + (size_t)((s + 1) & 1) * HPS + b3 * 768 + q * 8;
                    u64 h0 = ld64ws(src), h1 = ld64ws(src + 4);
                    u64* dh = (u64*)(actb + b3 * ASTR_B + (256 + q * 8) * 2);
                    dh[0] = h0; dh[1] = h1;
                    __syncthreads();
                    #pragma unroll
                    for (int fc = 0; fc < 4; ++fc) {
                        const int koff = ks * 128 + fc * 32 + quad * 8;
                        bf16x8 a0 = *(const bf16x8*)(actb + nl * ASTR_B + koff * 2);
                        bf16x8 a1 = *(const bf16x8*)(actb + (16 + nl) * ASTR_B + koff * 2);
                        acc0 = __builtin_amdgcn_mfma_f32_16x16x32_bf16(a0, bfr[fc], acc0, 0, 0, 0);
                        acc1 = __builtin_amdgcn_mfma_f32_16x16x32_bf16(a1, bfr[fc], acc1, 0, 0, 0);
                    }
                    __syncthreads();
                }
                // ---- chunk 1: K[512,1024) = hA(t-1)[256,768) ----
                {
                    const u16* base = hA + (size_t)((s + 1) & 1) * HPS + b3 * 768 + 256;
                    #pragma unroll
                    for (int p = 0; p < 2; ++p) {
                        const int k = q * 8 + 256 * p;
                        u64 h0 = ld64ws(base + k), h1 = ld64ws(base + k + 4);
                        u64* d = (u64*)(actb + b3 * ASTR_B + k * 2);
                        d[0] = h0; d[1] = h1;
                    }
                    __syncthreads();
                    #pragma unroll
                    for (int fc = 0; fc < 4; ++fc) {
                        const int koff = ks * 128 + fc * 32 + quad * 8;
                        bf16x8 a0 = *(const bf16x8*)(actb + nl * ASTR_B + koff * 2);
                        bf16x8 a1 = *(const bf16x8*)(actb + (16 + nl) * ASTR_B + koff * 2);
                        acc0 = __builtin_amdgcn_mfma_f32_16x16x32_bf16(a0, bfr[4 + fc], acc0, 0, 0, 0);
                        acc1 = __builtin_amdgcn_mfma_f32_16x16x32_bf16(a1, bfr[4 + fc], acc1, 0, 0, 0);
                    }
                    __syncthreads();
                }
            } else if (role == 1) {
                const int u = s - 1;
                #pragma unroll
                for (int c = 0; c < 2; ++c) {
                    const u16* ringp = (c == 0) ? (hA + (size_t)(u & 1) * HPS)
                                                : (hB + (size_t)((u + 1) & 1) * HPS);
                    const u16* base = ringp + b3 * 768;
                    #pragma unroll
                    for (int p = 0; p < 3; ++p) {
                        const int k = q * 8 + 256 * p;
                        u64 h0 = ld64ws(base + k), h1 = ld64ws(base + k + 4);
                        u64* d = (u64*)(actb + b3 * ASTR_B + k * 2);
                        d[0] = h0; d[1] = h1;
                    }
                    __syncthreads();
                    #pragma unroll
                    for (int fc = 0; fc < 6; ++fc) {
                        const int koff = ks * 192 + fc * 32 + quad * 8;
                        bf16x8 a0 = *(const bf16x8*)(actb + nl * ASTR_B + koff * 2);
                        bf16x8 a1 = *(const bf16x8*)(actb + (16 + nl) * ASTR_B + koff * 2);
                        acc0 = __builtin_amdgcn_mfma_f32_16x16x32_bf16(a0, bfr[c * 6 + fc], acc0, 0, 0, 0);
                        acc1 = __builtin_amdgcn_mfma_f32_16x16x32_bf16(a1, bfr[c * 6 + fc], acc1, 0, 0, 0);
                    }
                    __syncthreads();
                }
            } else {
                const u16* base = hB + (size_t)((s - 2) & 1) * HPS + b3 * 768;
                #pragma unroll
                for (int p = 0; p < 3; ++p) {
                    const int k = q * 8 + 256 * p;
                    u64 h0 = ld64ws(base + k), h1 = ld64ws(base + k + 4);
                    u64* d = (u64*)(actb + b3 * ASTR_B + k * 2);
                    d[0] = h0; d[1] = h1;
                }
                __syncthreads();
                #pragma unroll
                for (int fc = 0; fc < 6; ++fc) {
                    const int koff = ks * 192 + fc * 32 + quad * 8;
                    bf16x8 a0 = *(const bf16x8*)(actb + nl * ASTR_B + koff * 2);
                    bf16x8 a1 = *(const bf16x8*)(actb + (16 + nl) * ASTR_B + koff * 2);
                    acc0 = __builtin_amdgcn_mfma_f32_16x16x32_bf16(a0, bfr[fc], acc0, 0, 0, 0);
                    acc1 = __builtin_amdgcn_mfma_f32_16x16x32_bf16(a1, bfr[fc], acc1, 0, 0, 0);
                }
                __syncthreads();
            }

            // ---- C tiles -> red (act is dead; red region = first 32 KB) ----
            // D layout (R4-verified): col n=lane&15 (weight row), row m=quad*4+reg (batch).
            *(f32x4*)(red + (size_t)((nt * 2 + 0) * 4 + ks) * 256 + nl * 16 + quad * 4) = acc0;
            *(f32x4*)(red + (size_t)((nt * 2 + 1) * 4 + ks) * 256 + nl * 16 + quad * 4) = acc1;
            __syncthreads();

            // ---- K-reduction: thread (r2,bb) sums 4 slabs for rows r2 and r2+32 ----
            const int r2 = tid >> 5, bb = tid & 31;
            const int mtr = bb >> 4, mr = bb & 15;
            float s0 = 0.f, s1 = 0.f;
            {
                const int nt0 = r2 >> 4, nr0 = r2 & 15;
                const int nt1 = (r2 + 32) >> 4, nr1 = (r2 + 32) & 15;
                #pragma unroll
                for (int k2 = 0; k2 < 4; ++k2) {
                    s0 += red[(size_t)((nt0 * 2 + mtr) * 4 + k2) * 256 + nr0 * 16 + mr];
                    s1 += red[(size_t)((nt1 * 2 + mtr) * 4 + k2) * 256 + nr1 * 16 + mr];
                }
            }

            if (role == 2) {
                const int v = s - 2;
                float* o = out + ((size_t)bb * Tt + v) * OUTF + obase;
                o[r2]      = s0 + bl0;
                o[32 + r2] = s1 + bl1;
            } else {
                part[r2 * 33 + bb]        = s0;
                part[(r2 + 32) * 33 + bb] = s1;
                __syncthreads();
                // ---- gates (rows: gate g at g*16+jl) ----
                if (tid < 512) {
                    const int jl = tid >> 5, b2 = tid & 31;
                    const float pi = bs0 + part[(jl)      * 33 + b2];
                    const float pf = bs1 + part[(16 + jl) * 33 + b2];
                    const float pg = bs2 + part[(32 + jl) * 33 + b2];
                    const float po = bs3 + part[(48 + jl) * 33 + b2];
                    const float ig = sigf(pi), fg = sigf(pf);
                    const float gv = tanhf(pg), og = sigf(po);
                    creg = fg * creg + ig * gv;
                    hpack[jl * 32 + b2] = f2bf(og * tanhf(creg));
                }
                __syncthreads();
                if (tid < 256) {   // pack j-pairs -> u32 LLC store into ring
                    const int pp = tid >> 5, b2 = tid & 31;
                    const u32 val = (u32)hpack[(2 * pp) * 32 + b2]
                                  | ((u32)hpack[(2 * pp + 1) * 32 + b2] << 16);
                    u16* dst = (role == 0) ? (hA + (size_t)(s & 1) * HPS)
                                           : (hB + (size_t)((s - 1) & 1) * HPS);
                    st32ws(dst + b2 * 768 + jbase + 2 * pp, val);
                }
            }
        }

        // ---- publish progress on private line (after all stores drained) ----
        __syncthreads();
        if (tid == 0) stu32(prog + wg * 32, (u32)(s + 1));
    }
}

extern "C" void kernel_launch(void* const* d_in, const int* in_sizes, int n_in,
                              void* d_out, int out_size, void* d_ws, size_t ws_size,
                              hipStream_t stream)
{
    const float* x    = (const float*)d_in[0];
    const float* Wih0 = (const float*)d_in[1];
    const float* Whh0 = (const float*)d_in[2];
    const float* bih0 = (const float*)d_in[3];
    const float* bhh0 = (const float*)d_in[4];
    const float* Wih1 = (const float*)d_in[5];
    const float* Whh1 = (const float*)d_in[6];
    const float* bih1 = (const float*)d_in[7];
    const float* bhh1 = (const float*)d_in[8];
    const float* Wlin = (const float*)d_in[9];
    const float* blin = (const float*)d_in[10];
    float* out = (float*)d_out;
    char*  ws  = (char*)d_ws;   // uses WS_BYTES = 224 KB

    hipLaunchKernelGGL(prologue, dim3(224), dim3(256), 0, stream, ws);
    hipLaunchKernelGGL(lstm_persist, dim3(NWG), dim3(NTHR), 0, stream,
                       x, Wih0, Whh0, bih0, bhh0,
                       Wih1, Whh1, bih1, bhh1,
                       Wlin, blin, out, ws);
}